// Round 19
// baseline (151.279 us; speedup 1.0000x reference)
//
#include <hip/hip_runtime.h>
#include <math.h>

#define NIMG 32
#define HWDIM 512
#define NPIX (HWDIM * HWDIM)      // 262144
#define NB 256
#define RAD 4
#define TW 64
#define TH 64

struct W9 { float w[9]; };

__device__ __forceinline__ float clip01(float v) { return fminf(fmaxf(v, 0.0f), 1.0f); }

// ---------------------------------------------------------------------------
// Host-side replica of NumPy's FMA/AVX f32 exp (Pade P5/Q2 + scalef).
// ---------------------------------------------------------------------------
static float np_expf(float x) {
  const float LOG2E = 1.442695040f;
  const float CW_HI = -6.93145752e-1f;
  const float CW_LO = -1.42860677e-6f;
  const float P0 = 9.999999999980870924916e-01f;
  const float P1 = 7.257664613233124478488e-01f;
  const float P2 = 2.473615434895520810817e-01f;
  const float P3 = 5.114512081637298353406e-02f;
  const float P4 = 6.757896990527504603057e-03f;
  const float P5 = 5.082762527590693718096e-04f;
  const float Q0 = 1.000000000000000000000e+00f;
  const float Q1 = -2.742335390411667452936e-01f;
  const float Q2 = 2.159509375685829852307e-02f;
  float m = rintf(x * LOG2E);
  float y = fmaf(m, CW_HI, x);
  y = fmaf(m, CW_LO, y);
  float num = fmaf(fmaf(fmaf(fmaf(fmaf(P5, y, P4), y, P3), y, P2), y, P1), y, P0);
  float den = fmaf(fmaf(Q2, y, Q1), y, Q0);
  float r = num / den;
  return ldexpf(r, (int)m);
}

// ---------------------------------------------------------------------------
// blur: thermal + separable 9-tap (f64 accumulate per pass, f32 cast — r12
// certified). float4 bl stores (4 px/thread), float4 ch0 passthrough copy
// (re-reads hit L1), per-block min/max -> ws via plain stores.
// ---------------------------------------------------------------------------
__global__ __launch_bounds__(256) void blur_kernel(const float* __restrict__ x, float* __restrict__ out,
                                                   float* __restrict__ mnmx, W9 wp) {
  __shared__ float raw[TH + 8][TW + 8];
  __shared__ float vb[TH][TW + 8];
  const int img = blockIdx.z;
  const int blk = blockIdx.y * 8 + blockIdx.x;            // 0..63 within image
  const int tx0 = blockIdx.x * TW;
  const int ty0 = blockIdx.y * TH;
  const float* src = x + (size_t)img * 4 * NPIX;          // channel 0
  float* out0 = out + (size_t)img * 4 * NPIX;             // ch0 passthrough dest
  float* bl = out0 + NPIX;                                 // blurred staged in ch1
  const int tid = threadIdx.x;

  for (int i = tid; i < (TH + 8) * (TW + 8); i += 256) {
    int lr = i / (TW + 8), lc = i % (TW + 8);
    int gr = ty0 - RAD + lr; gr = gr < 0 ? 0 : (gr > HWDIM - 1 ? HWDIM - 1 : gr);
    int gc = tx0 - RAD + lc; gc = gc < 0 ? 0 : (gc > HWDIM - 1 ? HWDIM - 1 : gc);
    float v = src[gr * HWDIM + gc];
    raw[lr][lc] = clip01(__fadd_rn(__fmul_rn(v, 0.5f), 0.5f));
  }
  // ch0 passthrough: float4 copy of the central tile (reads hit L1/L2)
  {
    const float4* s4 = (const float4*)src;
    float4* o4 = (float4*)out0;
#pragma unroll
    for (int it = 0; it < 4; ++it) {
      int g = tid + it * 256;                 // 1024 groups = 64 rows x 16
      int r = g >> 4, c4 = g & 15;
      int idx = (ty0 + r) * (HWDIM / 4) + (tx0 >> 2) + c4;
      o4[idx] = s4[idx];
    }
  }
  __syncthreads();

  for (int i = tid; i < TH * (TW + 8); i += 256) {
    int r = i / (TW + 8), c = i % (TW + 8);
    double acc = 0.0;
#pragma unroll
    for (int k = 0; k < 9; ++k) acc += (double)wp.w[k] * (double)raw[r + k][c];
    vb[r][c] = (float)acc;           // f32 cast per pass
  }
  __syncthreads();

  float lmn = __int_as_float(0x7F800000);
  float lmx = 0.0f;
  float4* bl4 = (float4*)bl;
#pragma unroll
  for (int it = 0; it < 4; ++it) {
    int g = tid + it * 256;                   // 1024 groups of 4 px
    int r = g >> 4, c0 = (g & 15) * 4;
    double a0 = 0.0, a1 = 0.0, a2 = 0.0, a3 = 0.0;
#pragma unroll
    for (int k = 0; k < 9; ++k) {
      double wk = (double)wp.w[k];
      a0 += wk * (double)vb[r][c0 + k];
      a1 += wk * (double)vb[r][c0 + 1 + k];
      a2 += wk * (double)vb[r][c0 + 2 + k];
      a3 += wk * (double)vb[r][c0 + 3 + k];
    }
    float4 o;
    o.x = (float)a0; o.y = (float)a1; o.z = (float)a2; o.w = (float)a3;
    bl4[(ty0 + r) * (HWDIM / 4) + (tx0 >> 2) + (g & 15)] = o;
    lmn = fminf(lmn, fminf(fminf(o.x, o.y), fminf(o.z, o.w)));
    lmx = fmaxf(lmx, fmaxf(fmaxf(o.x, o.y), fmaxf(o.z, o.w)));
  }
  for (int off = 32; off > 0; off >>= 1) {
    lmn = fminf(lmn, __shfl_down(lmn, off, 64));
    lmx = fmaxf(lmx, __shfl_down(lmx, off, 64));
  }
  __shared__ float smn[4], smx[4];
  if ((tid & 63) == 0) { smn[tid >> 6] = lmn; smx[tid >> 6] = lmx; }
  __syncthreads();
  if (tid == 0) {
    float mnb = fminf(fminf(smn[0], smn[1]), fminf(smn[2], smn[3]));
    float mxb = fmaxf(fmaxf(smx[0], smx[1]), fmaxf(smx[2], smx[3]));
    mnmx[img * 128 + blk * 2] = mnb;       // plain stores — no init, no atomics
    mnmx[img * 128 + blk * 2 + 1] = mxb;
  }
}

// ---------------------------------------------------------------------------
// histotsu: one block per image, 1024 threads. Reduce the 64 (min,max) pairs
// (exact, order-free), build the full 256-bin histogram in 8-way LDS
// sub-hists (bl reads are L3-resident), then lane 0 runs the certified
// sequential-f32 Otsu. Binning + Otsu numerics bit-identical to r12..r18.
// ---------------------------------------------------------------------------
__global__ __launch_bounds__(1024) void histotsu_kernel(const float* __restrict__ mnmx,
                                                        const float* __restrict__ out,
                                                        float* __restrict__ t) {
  __shared__ int lh[8 * 260];
  __shared__ int h[NB];
  __shared__ float rs[NB + 1];
  __shared__ float s_mn, s_mx;
  const int img = blockIdx.x;
  const int tid = threadIdx.x;
  for (int i = tid; i < 8 * 260; i += 1024) lh[i] = 0;

  if (tid < 64) {
    float lmn = mnmx[img * 128 + tid * 2];
    float lmx = mnmx[img * 128 + tid * 2 + 1];
    for (int off = 32; off > 0; off >>= 1) {
      lmn = fminf(lmn, __shfl_down(lmn, off, 64));
      lmx = fmaxf(lmx, __shfl_down(lmx, off, 64));
    }
    if (tid == 0) { s_mn = lmn; s_mx = lmx; }
  }
  __syncthreads();
  const float mn = s_mn;
  const float rng = fmaxf(s_mx - mn, 1e-12f);

  const float4* src = (const float4*)(out + (size_t)img * 4 * NPIX + NPIX);
  int* my = lh + (tid & 7) * 260;
#pragma unroll 4
  for (int j = 0; j < 64; ++j) {
    float4 v = src[j * 1024 + tid];
    float q; int b;
    q = __fmul_rn(__fdiv_rn(__fsub_rn(v.x, mn), rng), 256.0f); b = (int)floorf(q); b = b < 0 ? 0 : (b > 255 ? 255 : b); atomicAdd(&my[b], 1);
    q = __fmul_rn(__fdiv_rn(__fsub_rn(v.y, mn), rng), 256.0f); b = (int)floorf(q); b = b < 0 ? 0 : (b > 255 ? 255 : b); atomicAdd(&my[b], 1);
    q = __fmul_rn(__fdiv_rn(__fsub_rn(v.z, mn), rng), 256.0f); b = (int)floorf(q); b = b < 0 ? 0 : (b > 255 ? 255 : b); atomicAdd(&my[b], 1);
    q = __fmul_rn(__fdiv_rn(__fsub_rn(v.w, mn), rng), 256.0f); b = (int)floorf(q); b = b < 0 ? 0 : (b > 255 ? 255 : b); atomicAdd(&my[b], 1);
  }
  __syncthreads();
  if (tid < NB) {
    int c = 0;
#pragma unroll
    for (int s = 0; s < 8; ++s) c += lh[s * 260 + tid];
    h[tid] = c;
  }
  __syncthreads();
  if (tid != 0) return;

  // certified sequential-f32 Otsu (bit-identical to r12..r18)
  const float scale = rng / 256.0f;   // exact
  float acc = 0.0f;
  rs[NB] = 0.0f;
  for (int i = NB - 1; i >= 0; --i) {
    float c = __fadd_rn(mn, __fmul_rn((float)i + 0.5f, scale));
    acc = __fadd_rn(acc, __fmul_rn((float)h[i], c));
    rs[i] = acc;
  }
  float w1 = 0.0f, cs1 = 0.0f, best = -INFINITY;
  int arg = 0;
  for (int i = 0; i < NB - 1; ++i) {
    float hi = (float)h[i];
    float c = __fadd_rn(mn, __fmul_rn((float)i + 0.5f, scale));
    w1 = __fadd_rn(w1, hi);
    cs1 = __fadd_rn(cs1, __fmul_rn(hi, c));
    float w2n = (float)NPIX - w1;
    float m1 = __fdiv_rn(cs1, fmaxf(w1, 1e-12f));
    float m2n = __fdiv_rn(rs[i + 1], fmaxf(w2n, 1e-12f));
    float d = __fsub_rn(m1, m2n);
    float v = __fmul_rn(__fmul_rn(w1, w2n), __fmul_rn(d, d));
    if (v > best) { best = v; arg = i; }
  }
  t[img] = __fadd_rn(mn, __fmul_rn((float)arg + 0.5f, scale));
}

// ---------------------------------------------------------------------------
// mask: ch1..3 = clip(alpha*rgb + (1-alpha)), alpha = bl > t ? 1 : bl.
// ch0 written by blur. Reads own bl float4 before overwriting.
// ---------------------------------------------------------------------------
__global__ __launch_bounds__(256) void mask_kernel(const float* __restrict__ x, const float* __restrict__ tarr,
                                                   float* __restrict__ out) {
  const int gid = blockIdx.x * 256 + threadIdx.x;
  const int img = gid >> 16;
  const int rem = gid & 65535;
  const float4* xb = (const float4*)(x + (size_t)img * 4 * NPIX);
  float4* ob = (float4*)(out + (size_t)img * 4 * NPIX);
  const float tv = tarr[img];

  float4 bl = ob[65536 + rem];        // blurred staged in ch1 — read before write
  float4 x1 = xb[65536 + rem];
  float4 x2 = xb[2 * 65536 + rem];
  float4 x3 = xb[3 * 65536 + rem];

  float a0 = bl.x > tv ? 1.0f : bl.x;
  float a1 = bl.y > tv ? 1.0f : bl.y;
  float a2 = bl.z > tv ? 1.0f : bl.z;
  float a3 = bl.w > tv ? 1.0f : bl.w;

  float4 o1, o2, o3;
  o1.x = clip01(__fadd_rn(__fmul_rn(a0, x1.x), 1.0f - a0));
  o1.y = clip01(__fadd_rn(__fmul_rn(a1, x1.y), 1.0f - a1));
  o1.z = clip01(__fadd_rn(__fmul_rn(a2, x1.z), 1.0f - a2));
  o1.w = clip01(__fadd_rn(__fmul_rn(a3, x1.w), 1.0f - a3));
  o2.x = clip01(__fadd_rn(__fmul_rn(a0, x2.x), 1.0f - a0));
  o2.y = clip01(__fadd_rn(__fmul_rn(a1, x2.y), 1.0f - a1));
  o2.z = clip01(__fadd_rn(__fmul_rn(a2, x2.z), 1.0f - a2));
  o2.w = clip01(__fadd_rn(__fmul_rn(a3, x2.w), 1.0f - a3));
  o3.x = clip01(__fadd_rn(__fmul_rn(a0, x3.x), 1.0f - a0));
  o3.y = clip01(__fadd_rn(__fmul_rn(a1, x3.y), 1.0f - a1));
  o3.z = clip01(__fadd_rn(__fmul_rn(a2, x3.z), 1.0f - a2));
  o3.w = clip01(__fadd_rn(__fmul_rn(a3, x3.w), 1.0f - a3));

  ob[65536 + rem] = o1;
  ob[2 * 65536 + rem] = o2;
  ob[3 * 65536 + rem] = o3;
}

extern "C" void kernel_launch(void* const* d_in, const int* in_sizes, int n_in,
                              void* d_out, int out_size, void* d_ws, size_t ws_size,
                              hipStream_t stream) {
  const float* x = (const float*)d_in[0];
  float* out = (float*)d_out;
  char* ws = (char*)d_ws;
  float* mnmx = (float*)(ws + 0);                 // 32*64*2 floats = 16 KB
  float* t = (float*)(ws + 32 * 128 * 4);         // 32 floats

  // Gaussian weights: numpy-SIMD f32 exp replica, numpy pairwise 9-sum, f32 div
  W9 wp;
  {
    float k[9];
    for (int i = 0; i < 9; ++i) {
      float xs = (float)(i - 4);
      float argv = -0.5f * (xs * xs);
      k[i] = np_expf(argv);
    }
    float s = ((k[0] + k[1]) + (k[2] + k[3])) + ((k[4] + k[5]) + (k[6] + k[7]));
    s = s + k[8];
    for (int i = 0; i < 9; ++i) wp.w[i] = k[i] / s;
  }

  hipLaunchKernelGGL(blur_kernel, dim3(HWDIM / TW, HWDIM / TH, NIMG), dim3(256), 0, stream,
                     x, out, mnmx, wp);
  hipLaunchKernelGGL(histotsu_kernel, dim3(NIMG), dim3(1024), 0, stream, mnmx, out, t);
  hipLaunchKernelGGL(mask_kernel, dim3(NIMG * NPIX / 4 / 256), dim3(256), 0, stream,
                     x, t, out);
}

// Round 20
// 129.600 us; speedup vs baseline: 1.1673x; 1.1673x over previous
//
#include <hip/hip_runtime.h>
#include <math.h>

#define NIMG 32
#define HWDIM 512
#define NPIX (HWDIM * HWDIM)      // 262144
#define NB 256
#define RAD 4
#define TW 64
#define TH 64

struct W9 { float w[9]; };

__device__ __forceinline__ float clip01(float v) { return fminf(fmaxf(v, 0.0f), 1.0f); }

// ---------------------------------------------------------------------------
// Host-side replica of NumPy's FMA/AVX f32 exp (Pade P5/Q2 + scalef).
// ---------------------------------------------------------------------------
static float np_expf(float x) {
  const float LOG2E = 1.442695040f;
  const float CW_HI = -6.93145752e-1f;
  const float CW_LO = -1.42860677e-6f;
  const float P0 = 9.999999999980870924916e-01f;
  const float P1 = 7.257664613233124478488e-01f;
  const float P2 = 2.473615434895520810817e-01f;
  const float P3 = 5.114512081637298353406e-02f;
  const float P4 = 6.757896990527504603057e-03f;
  const float P5 = 5.082762527590693718096e-04f;
  const float Q0 = 1.000000000000000000000e+00f;
  const float Q1 = -2.742335390411667452936e-01f;
  const float Q2 = 2.159509375685829852307e-02f;
  float m = rintf(x * LOG2E);
  float y = fmaf(m, CW_HI, x);
  y = fmaf(m, CW_LO, y);
  float num = fmaf(fmaf(fmaf(fmaf(fmaf(P5, y, P4), y, P3), y, P2), y, P1), y, P0);
  float den = fmaf(fmaf(Q2, y, Q1), y, Q0);
  float r = num / den;
  return ldexpf(r, (int)m);
}

// ---------------------------------------------------------------------------
// blur: thermal + separable 9-tap (f64 accumulate per pass, f32 cast — r12
// certified). float4 bl stores (4 px/thread), float4 ch0 passthrough copy,
// per-block min/max -> ws via plain stores (no init, no atomics).
// ---------------------------------------------------------------------------
__global__ __launch_bounds__(256) void blur_kernel(const float* __restrict__ x, float* __restrict__ out,
                                                   float* __restrict__ mnmx, W9 wp) {
  __shared__ float raw[TH + 8][TW + 8];
  __shared__ float vb[TH][TW + 8];
  const int img = blockIdx.z;
  const int blk = blockIdx.y * 8 + blockIdx.x;            // 0..63 within image
  const int tx0 = blockIdx.x * TW;
  const int ty0 = blockIdx.y * TH;
  const float* src = x + (size_t)img * 4 * NPIX;          // channel 0
  float* out0 = out + (size_t)img * 4 * NPIX;             // ch0 passthrough dest
  float* bl = out0 + NPIX;                                 // blurred staged in ch1
  const int tid = threadIdx.x;

  for (int i = tid; i < (TH + 8) * (TW + 8); i += 256) {
    int lr = i / (TW + 8), lc = i % (TW + 8);
    int gr = ty0 - RAD + lr; gr = gr < 0 ? 0 : (gr > HWDIM - 1 ? HWDIM - 1 : gr);
    int gc = tx0 - RAD + lc; gc = gc < 0 ? 0 : (gc > HWDIM - 1 ? HWDIM - 1 : gc);
    float v = src[gr * HWDIM + gc];
    raw[lr][lc] = clip01(__fadd_rn(__fmul_rn(v, 0.5f), 0.5f));
  }
  // ch0 passthrough: float4 copy of the central tile (reads hit L1/L2)
  {
    const float4* s4 = (const float4*)src;
    float4* o4 = (float4*)out0;
#pragma unroll
    for (int it = 0; it < 4; ++it) {
      int g = tid + it * 256;                 // 1024 groups = 64 rows x 16
      int r = g >> 4, c4 = g & 15;
      int idx = (ty0 + r) * (HWDIM / 4) + (tx0 >> 2) + c4;
      o4[idx] = s4[idx];
    }
  }
  __syncthreads();

  for (int i = tid; i < TH * (TW + 8); i += 256) {
    int r = i / (TW + 8), c = i % (TW + 8);
    double acc = 0.0;
#pragma unroll
    for (int k = 0; k < 9; ++k) acc += (double)wp.w[k] * (double)raw[r + k][c];
    vb[r][c] = (float)acc;           // f32 cast per pass
  }
  __syncthreads();

  float lmn = __int_as_float(0x7F800000);
  float lmx = 0.0f;
  float4* bl4 = (float4*)bl;
#pragma unroll
  for (int it = 0; it < 4; ++it) {
    int g = tid + it * 256;                   // 1024 groups of 4 px
    int r = g >> 4, c0 = (g & 15) * 4;
    double a0 = 0.0, a1 = 0.0, a2 = 0.0, a3 = 0.0;
#pragma unroll
    for (int k = 0; k < 9; ++k) {
      double wk = (double)wp.w[k];
      a0 += wk * (double)vb[r][c0 + k];
      a1 += wk * (double)vb[r][c0 + 1 + k];
      a2 += wk * (double)vb[r][c0 + 2 + k];
      a3 += wk * (double)vb[r][c0 + 3 + k];
    }
    float4 o;
    o.x = (float)a0; o.y = (float)a1; o.z = (float)a2; o.w = (float)a3;
    bl4[(ty0 + r) * (HWDIM / 4) + (tx0 >> 2) + (g & 15)] = o;
    lmn = fminf(lmn, fminf(fminf(o.x, o.y), fminf(o.z, o.w)));
    lmx = fmaxf(lmx, fmaxf(fmaxf(o.x, o.y), fmaxf(o.z, o.w)));
  }
  for (int off = 32; off > 0; off >>= 1) {
    lmn = fminf(lmn, __shfl_down(lmn, off, 64));
    lmx = fmaxf(lmx, __shfl_down(lmx, off, 64));
  }
  __shared__ float smn[4], smx[4];
  if ((tid & 63) == 0) { smn[tid >> 6] = lmn; smx[tid >> 6] = lmx; }
  __syncthreads();
  if (tid == 0) {
    float mnb = fminf(fminf(smn[0], smn[1]), fminf(smn[2], smn[3]));
    float mxb = fmaxf(fmaxf(smx[0], smx[1]), fmaxf(smx[2], smx[3]));
    mnmx[img * 128 + blk * 2] = mnb;
    mnmx[img * 128 + blk * 2 + 1] = mxb;
  }
}

// ---------------------------------------------------------------------------
// hist: prologue reduces the 64 per-block (min,max) pairs (exact, order-free),
// bins 16 px/thread into 4-way LDS sub-hists (pitch 260), writes this block's
// 256-int PARTIAL histogram (plain stores) into the ch2 slot of d_out.
// Binning formula bit-identical to r12..r18.
// ---------------------------------------------------------------------------
__global__ __launch_bounds__(256) void hist_kernel(const float* __restrict__ mnmx, float* __restrict__ out) {
  __shared__ int lh[4 * 260];
  __shared__ float s_mn, s_mx;
  const int img = blockIdx.y;
  const int p = blockIdx.x;            // 0..63
  const int tid = threadIdx.x;
  for (int i = tid; i < 4 * 260; i += 256) lh[i] = 0;

  float lmn = __int_as_float(0x7F800000);
  float lmx = 0.0f;
  if (tid < 64) {
    lmn = mnmx[img * 128 + tid * 2];
    lmx = mnmx[img * 128 + tid * 2 + 1];
    for (int off = 32; off > 0; off >>= 1) {
      lmn = fminf(lmn, __shfl_down(lmn, off, 64));
      lmx = fmaxf(lmx, __shfl_down(lmx, off, 64));
    }
    if (tid == 0) { s_mn = lmn; s_mx = lmx; }
  }
  __syncthreads();
  const float mn = s_mn;
  const float mx = s_mx;
  const float rng = fmaxf(mx - mn, 1e-12f);

  const float4* src = (const float4*)(out + (size_t)img * 4 * NPIX + NPIX);
  int* my = lh + (tid & 3) * 260;
#pragma unroll
  for (int j = 0; j < 4; ++j) {
    float4 v = src[p * 1024 + j * 256 + tid];
    float q; int b;
    q = __fmul_rn(__fdiv_rn(__fsub_rn(v.x, mn), rng), 256.0f); b = (int)floorf(q); b = b < 0 ? 0 : (b > 255 ? 255 : b); atomicAdd(&my[b], 1);
    q = __fmul_rn(__fdiv_rn(__fsub_rn(v.y, mn), rng), 256.0f); b = (int)floorf(q); b = b < 0 ? 0 : (b > 255 ? 255 : b); atomicAdd(&my[b], 1);
    q = __fmul_rn(__fdiv_rn(__fsub_rn(v.z, mn), rng), 256.0f); b = (int)floorf(q); b = b < 0 ? 0 : (b > 255 ? 255 : b); atomicAdd(&my[b], 1);
    q = __fmul_rn(__fdiv_rn(__fsub_rn(v.w, mn), rng), 256.0f); b = (int)floorf(q); b = b < 0 ? 0 : (b > 255 ? 255 : b); atomicAdd(&my[b], 1);
  }
  __syncthreads();
  int c = lh[tid] + lh[260 + tid] + lh[2 * 260 + tid] + lh[3 * 260 + tid];
  int* part = (int*)(out + (size_t)img * 4 * NPIX + 2 * NPIX);   // ch2 staging
  part[p * NB + tid] = c;              // plain store — no init, no atomics
}

// ---------------------------------------------------------------------------
// otsu: 32 blocks x 256 threads. Sum the 64 integer partials per bin (exact),
// reduce min/max pairs, then lane 0 runs the certified sequential-f32 loops
// from LDS. Numerics bit-identical to r12..r18.
// ---------------------------------------------------------------------------
__global__ __launch_bounds__(256) void otsu_kernel(const float* __restrict__ mnmx, const float* __restrict__ out,
                                                   float* __restrict__ t) {
  __shared__ int h[NB];
  __shared__ float rs[NB + 1];
  __shared__ float s_mn, s_mx;
  const int img = blockIdx.x;
  const int tid = threadIdx.x;
  const int* part = (const int*)(out + (size_t)img * 4 * NPIX + 2 * NPIX);
  int sum = 0;
#pragma unroll 8
  for (int p = 0; p < 64; ++p) sum += part[p * NB + tid];
  h[tid] = sum;

  float lmn = __int_as_float(0x7F800000);
  float lmx = 0.0f;
  if (tid < 64) {
    lmn = mnmx[img * 128 + tid * 2];
    lmx = mnmx[img * 128 + tid * 2 + 1];
    for (int off = 32; off > 0; off >>= 1) {
      lmn = fminf(lmn, __shfl_down(lmn, off, 64));
      lmx = fmaxf(lmx, __shfl_down(lmx, off, 64));
    }
    if (tid == 0) { s_mn = lmn; s_mx = lmx; }
  }
  __syncthreads();
  if (tid != 0) return;

  const float mn = s_mn;
  const float mx = s_mx;
  const float rng = fmaxf(mx - mn, 1e-12f);
  const float scale = rng / 256.0f;   // exact

  float acc = 0.0f;
  rs[NB] = 0.0f;
  for (int i = NB - 1; i >= 0; --i) {
    float c = __fadd_rn(mn, __fmul_rn((float)i + 0.5f, scale));
    acc = __fadd_rn(acc, __fmul_rn((float)h[i], c));
    rs[i] = acc;
  }

  float w1 = 0.0f, cs1 = 0.0f, best = -INFINITY;
  int arg = 0;
  for (int i = 0; i < NB - 1; ++i) {
    float hi = (float)h[i];
    float c = __fadd_rn(mn, __fmul_rn((float)i + 0.5f, scale));
    w1 = __fadd_rn(w1, hi);
    cs1 = __fadd_rn(cs1, __fmul_rn(hi, c));
    float w2n = (float)NPIX - w1;
    float m1 = __fdiv_rn(cs1, fmaxf(w1, 1e-12f));
    float m2n = __fdiv_rn(rs[i + 1], fmaxf(w2n, 1e-12f));
    float d = __fsub_rn(m1, m2n);
    float v = __fmul_rn(__fmul_rn(w1, w2n), __fmul_rn(d, d));
    if (v > best) { best = v; arg = i; }
  }
  t[img] = __fadd_rn(mn, __fmul_rn((float)arg + 0.5f, scale));
}

// ---------------------------------------------------------------------------
// mask: ch1..3 = clip(alpha*rgb + (1-alpha)), alpha = bl > t ? 1 : bl.
// ch0 written by blur; ch2 staging overwritten here after otsu consumed it.
// ---------------------------------------------------------------------------
__global__ __launch_bounds__(256) void mask_kernel(const float* __restrict__ x, const float* __restrict__ tarr,
                                                   float* __restrict__ out) {
  const int gid = blockIdx.x * 256 + threadIdx.x;
  const int img = gid >> 16;
  const int rem = gid & 65535;
  const float4* xb = (const float4*)(x + (size_t)img * 4 * NPIX);
  float4* ob = (float4*)(out + (size_t)img * 4 * NPIX);
  const float tv = tarr[img];

  float4 bl = ob[65536 + rem];        // blurred staged in ch1 — read before write
  float4 x1 = xb[65536 + rem];
  float4 x2 = xb[2 * 65536 + rem];
  float4 x3 = xb[3 * 65536 + rem];

  float a0 = bl.x > tv ? 1.0f : bl.x;
  float a1 = bl.y > tv ? 1.0f : bl.y;
  float a2 = bl.z > tv ? 1.0f : bl.z;
  float a3 = bl.w > tv ? 1.0f : bl.w;

  float4 o1, o2, o3;
  o1.x = clip01(__fadd_rn(__fmul_rn(a0, x1.x), 1.0f - a0));
  o1.y = clip01(__fadd_rn(__fmul_rn(a1, x1.y), 1.0f - a1));
  o1.z = clip01(__fadd_rn(__fmul_rn(a2, x1.z), 1.0f - a2));
  o1.w = clip01(__fadd_rn(__fmul_rn(a3, x1.w), 1.0f - a3));
  o2.x = clip01(__fadd_rn(__fmul_rn(a0, x2.x), 1.0f - a0));
  o2.y = clip01(__fadd_rn(__fmul_rn(a1, x2.y), 1.0f - a1));
  o2.z = clip01(__fadd_rn(__fmul_rn(a2, x2.z), 1.0f - a2));
  o2.w = clip01(__fadd_rn(__fmul_rn(a3, x2.w), 1.0f - a3));
  o3.x = clip01(__fadd_rn(__fmul_rn(a0, x3.x), 1.0f - a0));
  o3.y = clip01(__fadd_rn(__fmul_rn(a1, x3.y), 1.0f - a1));
  o3.z = clip01(__fadd_rn(__fmul_rn(a2, x3.z), 1.0f - a2));
  o3.w = clip01(__fadd_rn(__fmul_rn(a3, x3.w), 1.0f - a3));

  ob[65536 + rem] = o1;
  ob[2 * 65536 + rem] = o2;
  ob[3 * 65536 + rem] = o3;
}

extern "C" void kernel_launch(void* const* d_in, const int* in_sizes, int n_in,
                              void* d_out, int out_size, void* d_ws, size_t ws_size,
                              hipStream_t stream) {
  const float* x = (const float*)d_in[0];
  float* out = (float*)d_out;
  char* ws = (char*)d_ws;
  float* mnmx = (float*)(ws + 0);                 // 32*64*2 floats = 16 KB
  float* t = (float*)(ws + 32 * 128 * 4);         // 32 floats

  // Gaussian weights: numpy-SIMD f32 exp replica, numpy pairwise 9-sum, f32 div
  W9 wp;
  {
    float k[9];
    for (int i = 0; i < 9; ++i) {
      float xs = (float)(i - 4);
      float argv = -0.5f * (xs * xs);
      k[i] = np_expf(argv);
    }
    float s = ((k[0] + k[1]) + (k[2] + k[3])) + ((k[4] + k[5]) + (k[6] + k[7]));
    s = s + k[8];
    for (int i = 0; i < 9; ++i) wp.w[i] = k[i] / s;
  }

  hipLaunchKernelGGL(blur_kernel, dim3(HWDIM / TW, HWDIM / TH, NIMG), dim3(256), 0, stream,
                     x, out, mnmx, wp);
  hipLaunchKernelGGL(hist_kernel, dim3(64, NIMG), dim3(256), 0, stream, mnmx, out);
  hipLaunchKernelGGL(otsu_kernel, dim3(NIMG), dim3(256), 0, stream, mnmx, out, t);
  hipLaunchKernelGGL(mask_kernel, dim3(NIMG * NPIX / 4 / 256), dim3(256), 0, stream,
                     x, t, out);
}

// Round 21
// 126.614 us; speedup vs baseline: 1.1948x; 1.0236x over previous
//
#include <hip/hip_runtime.h>
#include <math.h>

#define NIMG 32
#define HWDIM 512
#define NPIX (HWDIM * HWDIM)      // 262144
#define NB 256
#define RAD 4
#define TW 64
#define TH 64

struct W9 { float w[9]; };

__device__ __forceinline__ float clip01(float v) { return fminf(fmaxf(v, 0.0f), 1.0f); }

// ---------------------------------------------------------------------------
// Host-side replica of NumPy's FMA/AVX f32 exp (Pade P5/Q2 + scalef).
// ---------------------------------------------------------------------------
static float np_expf(float x) {
  const float LOG2E = 1.442695040f;
  const float CW_HI = -6.93145752e-1f;
  const float CW_LO = -1.42860677e-6f;
  const float P0 = 9.999999999980870924916e-01f;
  const float P1 = 7.257664613233124478488e-01f;
  const float P2 = 2.473615434895520810817e-01f;
  const float P3 = 5.114512081637298353406e-02f;
  const float P4 = 6.757896990527504603057e-03f;
  const float P5 = 5.082762527590693718096e-04f;
  const float Q0 = 1.000000000000000000000e+00f;
  const float Q1 = -2.742335390411667452936e-01f;
  const float Q2 = 2.159509375685829852307e-02f;
  float m = rintf(x * LOG2E);
  float y = fmaf(m, CW_HI, x);
  y = fmaf(m, CW_LO, y);
  float num = fmaf(fmaf(fmaf(fmaf(fmaf(P5, y, P4), y, P3), y, P2), y, P1), y, P0);
  float den = fmaf(fmaf(Q2, y, Q1), y, Q0);
  float r = num / den;
  return ldexpf(r, (int)m);
}

// ---------------------------------------------------------------------------
// blur: thermal + separable 9-tap (f64 accumulate per pass, f32 cast — r12
// certified). LDS traffic vectorized to ds_read_b128/ds_write_b128 (4 px per
// thread in both passes; same per-output f64 ascending-k order -> bit-exact).
// float4 bl stores, float4 ch0 passthrough, per-block min/max plain stores.
// ---------------------------------------------------------------------------
__global__ __launch_bounds__(256) void blur_kernel(const float* __restrict__ x, float* __restrict__ out,
                                                   float* __restrict__ mnmx, W9 wp) {
  __shared__ float raw[TH + 8][TW + 8];     // row stride 288 B (16B-aligned)
  __shared__ float vb[TH][TW + 8];
  const int img = blockIdx.z;
  const int blk = blockIdx.y * 8 + blockIdx.x;            // 0..63 within image
  const int tx0 = blockIdx.x * TW;
  const int ty0 = blockIdx.y * TH;
  const float* src = x + (size_t)img * 4 * NPIX;          // channel 0
  float* out0 = out + (size_t)img * 4 * NPIX;             // ch0 passthrough dest
  float* bl = out0 + NPIX;                                 // blurred staged in ch1
  const int tid = threadIdx.x;

  for (int i = tid; i < (TH + 8) * (TW + 8); i += 256) {
    int lr = i / (TW + 8), lc = i % (TW + 8);
    int gr = ty0 - RAD + lr; gr = gr < 0 ? 0 : (gr > HWDIM - 1 ? HWDIM - 1 : gr);
    int gc = tx0 - RAD + lc; gc = gc < 0 ? 0 : (gc > HWDIM - 1 ? HWDIM - 1 : gc);
    float v = src[gr * HWDIM + gc];
    raw[lr][lc] = clip01(__fadd_rn(__fmul_rn(v, 0.5f), 0.5f));
  }
  // ch0 passthrough: float4 copy of the central tile (reads hit L1/L2)
  {
    const float4* s4 = (const float4*)src;
    float4* o4 = (float4*)out0;
#pragma unroll
    for (int it = 0; it < 4; ++it) {
      int g = tid + it * 256;                 // 1024 groups = 64 rows x 16
      int r = g >> 4, c4 = g & 15;
      int idx = (ty0 + r) * (HWDIM / 4) + (tx0 >> 2) + c4;
      o4[idx] = s4[idx];
    }
  }
  __syncthreads();

  // vertical pass: 4 adjacent columns per thread; 9 x float4 LDS reads
  for (int i = tid; i < TH * 18; i += 256) {   // 64 rows x 18 col-groups
    int r = i / 18, c4 = (i % 18) * 4;
    double a0 = 0.0, a1 = 0.0, a2 = 0.0, a3 = 0.0;
#pragma unroll
    for (int k = 0; k < 9; ++k) {
      float4 v = *(const float4*)&raw[r + k][c4];
      double wk = (double)wp.w[k];
      a0 += wk * (double)v.x;
      a1 += wk * (double)v.y;
      a2 += wk * (double)v.z;
      a3 += wk * (double)v.w;
    }
    float4 o;
    o.x = (float)a0; o.y = (float)a1; o.z = (float)a2; o.w = (float)a3;
    *(float4*)&vb[r][c4] = o;
  }
  __syncthreads();

  // horizontal pass: 4 adjacent outputs per thread; 3 x float4 LDS reads
  float lmn = __int_as_float(0x7F800000);
  float lmx = 0.0f;
  float4* bl4 = (float4*)bl;
#pragma unroll
  for (int it = 0; it < 4; ++it) {
    int g = tid + it * 256;                   // 1024 groups of 4 px
    int r = g >> 4, c0 = (g & 15) * 4;
    float4 v0 = *(const float4*)&vb[r][c0];
    float4 v1 = *(const float4*)&vb[r][c0 + 4];
    float4 v2 = *(const float4*)&vb[r][c0 + 8];
    float vv[12] = {v0.x, v0.y, v0.z, v0.w, v1.x, v1.y, v1.z, v1.w,
                    v2.x, v2.y, v2.z, v2.w};
    double a0 = 0.0, a1 = 0.0, a2 = 0.0, a3 = 0.0;
#pragma unroll
    for (int k = 0; k < 9; ++k) {
      double wk = (double)wp.w[k];
      a0 += wk * (double)vv[k];
      a1 += wk * (double)vv[k + 1];
      a2 += wk * (double)vv[k + 2];
      a3 += wk * (double)vv[k + 3];
    }
    float4 o;
    o.x = (float)a0; o.y = (float)a1; o.z = (float)a2; o.w = (float)a3;
    bl4[(ty0 + r) * (HWDIM / 4) + (tx0 >> 2) + (g & 15)] = o;
    lmn = fminf(lmn, fminf(fminf(o.x, o.y), fminf(o.z, o.w)));
    lmx = fmaxf(lmx, fmaxf(fmaxf(o.x, o.y), fmaxf(o.z, o.w)));
  }
  for (int off = 32; off > 0; off >>= 1) {
    lmn = fminf(lmn, __shfl_down(lmn, off, 64));
    lmx = fmaxf(lmx, __shfl_down(lmx, off, 64));
  }
  __shared__ float smn[4], smx[4];
  if ((tid & 63) == 0) { smn[tid >> 6] = lmn; smx[tid >> 6] = lmx; }
  __syncthreads();
  if (tid == 0) {
    float mnb = fminf(fminf(smn[0], smn[1]), fminf(smn[2], smn[3]));
    float mxb = fmaxf(fmaxf(smx[0], smx[1]), fmaxf(smx[2], smx[3]));
    mnmx[img * 128 + blk * 2] = mnb;
    mnmx[img * 128 + blk * 2 + 1] = mxb;
  }
}

// ---------------------------------------------------------------------------
// hist: prologue reduces the 64 per-block (min,max) pairs (exact, order-free),
// bins 16 px/thread into 4-way LDS sub-hists (pitch 260), writes this block's
// 256-int PARTIAL histogram (plain stores) into the ch2 slot of d_out.
// Binning formula bit-identical to r12..r20.
// ---------------------------------------------------------------------------
__global__ __launch_bounds__(256) void hist_kernel(const float* __restrict__ mnmx, float* __restrict__ out) {
  __shared__ int lh[4 * 260];
  __shared__ float s_mn, s_mx;
  const int img = blockIdx.y;
  const int p = blockIdx.x;            // 0..63
  const int tid = threadIdx.x;
  for (int i = tid; i < 4 * 260; i += 256) lh[i] = 0;

  float lmn = __int_as_float(0x7F800000);
  float lmx = 0.0f;
  if (tid < 64) {
    lmn = mnmx[img * 128 + tid * 2];
    lmx = mnmx[img * 128 + tid * 2 + 1];
    for (int off = 32; off > 0; off >>= 1) {
      lmn = fminf(lmn, __shfl_down(lmn, off, 64));
      lmx = fmaxf(lmx, __shfl_down(lmx, off, 64));
    }
    if (tid == 0) { s_mn = lmn; s_mx = lmx; }
  }
  __syncthreads();
  const float mn = s_mn;
  const float mx = s_mx;
  const float rng = fmaxf(mx - mn, 1e-12f);

  const float4* src = (const float4*)(out + (size_t)img * 4 * NPIX + NPIX);
  int* my = lh + (tid & 3) * 260;
#pragma unroll
  for (int j = 0; j < 4; ++j) {
    float4 v = src[p * 1024 + j * 256 + tid];
    float q; int b;
    q = __fmul_rn(__fdiv_rn(__fsub_rn(v.x, mn), rng), 256.0f); b = (int)floorf(q); b = b < 0 ? 0 : (b > 255 ? 255 : b); atomicAdd(&my[b], 1);
    q = __fmul_rn(__fdiv_rn(__fsub_rn(v.y, mn), rng), 256.0f); b = (int)floorf(q); b = b < 0 ? 0 : (b > 255 ? 255 : b); atomicAdd(&my[b], 1);
    q = __fmul_rn(__fdiv_rn(__fsub_rn(v.z, mn), rng), 256.0f); b = (int)floorf(q); b = b < 0 ? 0 : (b > 255 ? 255 : b); atomicAdd(&my[b], 1);
    q = __fmul_rn(__fdiv_rn(__fsub_rn(v.w, mn), rng), 256.0f); b = (int)floorf(q); b = b < 0 ? 0 : (b > 255 ? 255 : b); atomicAdd(&my[b], 1);
  }
  __syncthreads();
  int c = lh[tid] + lh[260 + tid] + lh[2 * 260 + tid] + lh[3 * 260 + tid];
  int* part = (int*)(out + (size_t)img * 4 * NPIX + 2 * NPIX);   // ch2 staging
  part[p * NB + tid] = c;              // plain store — no init, no atomics
}

// ---------------------------------------------------------------------------
// otsu: 32 blocks x 256 threads. Sum the 64 integer partials per bin (exact),
// reduce min/max pairs, then lane 0 runs the certified sequential-f32 loops
// from LDS. Numerics bit-identical to r12..r20.
// ---------------------------------------------------------------------------
__global__ __launch_bounds__(256) void otsu_kernel(const float* __restrict__ mnmx, const float* __restrict__ out,
                                                   float* __restrict__ t) {
  __shared__ int h[NB];
  __shared__ float rs[NB + 1];
  __shared__ float s_mn, s_mx;
  const int img = blockIdx.x;
  const int tid = threadIdx.x;
  const int* part = (const int*)(out + (size_t)img * 4 * NPIX + 2 * NPIX);
  int sum = 0;
#pragma unroll 8
  for (int p = 0; p < 64; ++p) sum += part[p * NB + tid];
  h[tid] = sum;

  float lmn = __int_as_float(0x7F800000);
  float lmx = 0.0f;
  if (tid < 64) {
    lmn = mnmx[img * 128 + tid * 2];
    lmx = mnmx[img * 128 + tid * 2 + 1];
    for (int off = 32; off > 0; off >>= 1) {
      lmn = fminf(lmn, __shfl_down(lmn, off, 64));
      lmx = fmaxf(lmx, __shfl_down(lmx, off, 64));
    }
    if (tid == 0) { s_mn = lmn; s_mx = lmx; }
  }
  __syncthreads();
  if (tid != 0) return;

  const float mn = s_mn;
  const float mx = s_mx;
  const float rng = fmaxf(mx - mn, 1e-12f);
  const float scale = rng / 256.0f;   // exact

  float acc = 0.0f;
  rs[NB] = 0.0f;
  for (int i = NB - 1; i >= 0; --i) {
    float c = __fadd_rn(mn, __fmul_rn((float)i + 0.5f, scale));
    acc = __fadd_rn(acc, __fmul_rn((float)h[i], c));
    rs[i] = acc;
  }

  float w1 = 0.0f, cs1 = 0.0f, best = -INFINITY;
  int arg = 0;
  for (int i = 0; i < NB - 1; ++i) {
    float hi = (float)h[i];
    float c = __fadd_rn(mn, __fmul_rn((float)i + 0.5f, scale));
    w1 = __fadd_rn(w1, hi);
    cs1 = __fadd_rn(cs1, __fmul_rn(hi, c));
    float w2n = (float)NPIX - w1;
    float m1 = __fdiv_rn(cs1, fmaxf(w1, 1e-12f));
    float m2n = __fdiv_rn(rs[i + 1], fmaxf(w2n, 1e-12f));
    float d = __fsub_rn(m1, m2n);
    float v = __fmul_rn(__fmul_rn(w1, w2n), __fmul_rn(d, d));
    if (v > best) { best = v; arg = i; }
  }
  t[img] = __fadd_rn(mn, __fmul_rn((float)arg + 0.5f, scale));
}

// ---------------------------------------------------------------------------
// mask: ch1..3 = clip(alpha*rgb + (1-alpha)), alpha = bl > t ? 1 : bl.
// ch0 written by blur; ch2 staging overwritten here after otsu consumed it.
// ---------------------------------------------------------------------------
__global__ __launch_bounds__(256) void mask_kernel(const float* __restrict__ x, const float* __restrict__ tarr,
                                                   float* __restrict__ out) {
  const int gid = blockIdx.x * 256 + threadIdx.x;
  const int img = gid >> 16;
  const int rem = gid & 65535;
  const float4* xb = (const float4*)(x + (size_t)img * 4 * NPIX);
  float4* ob = (float4*)(out + (size_t)img * 4 * NPIX);
  const float tv = tarr[img];

  float4 bl = ob[65536 + rem];        // blurred staged in ch1 — read before write
  float4 x1 = xb[65536 + rem];
  float4 x2 = xb[2 * 65536 + rem];
  float4 x3 = xb[3 * 65536 + rem];

  float a0 = bl.x > tv ? 1.0f : bl.x;
  float a1 = bl.y > tv ? 1.0f : bl.y;
  float a2 = bl.z > tv ? 1.0f : bl.z;
  float a3 = bl.w > tv ? 1.0f : bl.w;

  float4 o1, o2, o3;
  o1.x = clip01(__fadd_rn(__fmul_rn(a0, x1.x), 1.0f - a0));
  o1.y = clip01(__fadd_rn(__fmul_rn(a1, x1.y), 1.0f - a1));
  o1.z = clip01(__fadd_rn(__fmul_rn(a2, x1.z), 1.0f - a2));
  o1.w = clip01(__fadd_rn(__fmul_rn(a3, x1.w), 1.0f - a3));
  o2.x = clip01(__fadd_rn(__fmul_rn(a0, x2.x), 1.0f - a0));
  o2.y = clip01(__fadd_rn(__fmul_rn(a1, x2.y), 1.0f - a1));
  o2.z = clip01(__fadd_rn(__fmul_rn(a2, x2.z), 1.0f - a2));
  o2.w = clip01(__fadd_rn(__fmul_rn(a3, x2.w), 1.0f - a3));
  o3.x = clip01(__fadd_rn(__fmul_rn(a0, x3.x), 1.0f - a0));
  o3.y = clip01(__fadd_rn(__fmul_rn(a1, x3.y), 1.0f - a1));
  o3.z = clip01(__fadd_rn(__fmul_rn(a2, x3.z), 1.0f - a2));
  o3.w = clip01(__fadd_rn(__fmul_rn(a3, x3.w), 1.0f - a3));

  ob[65536 + rem] = o1;
  ob[2 * 65536 + rem] = o2;
  ob[3 * 65536 + rem] = o3;
}

extern "C" void kernel_launch(void* const* d_in, const int* in_sizes, int n_in,
                              void* d_out, int out_size, void* d_ws, size_t ws_size,
                              hipStream_t stream) {
  const float* x = (const float*)d_in[0];
  float* out = (float*)d_out;
  char* ws = (char*)d_ws;
  float* mnmx = (float*)(ws + 0);                 // 32*64*2 floats = 16 KB
  float* t = (float*)(ws + 32 * 128 * 4);         // 32 floats

  // Gaussian weights: numpy-SIMD f32 exp replica, numpy pairwise 9-sum, f32 div
  W9 wp;
  {
    float k[9];
    for (int i = 0; i < 9; ++i) {
      float xs = (float)(i - 4);
      float argv = -0.5f * (xs * xs);
      k[i] = np_expf(argv);
    }
    float s = ((k[0] + k[1]) + (k[2] + k[3])) + ((k[4] + k[5]) + (k[6] + k[7]));
    s = s + k[8];
    for (int i = 0; i < 9; ++i) wp.w[i] = k[i] / s;
  }

  hipLaunchKernelGGL(blur_kernel, dim3(HWDIM / TW, HWDIM / TH, NIMG), dim3(256), 0, stream,
                     x, out, mnmx, wp);
  hipLaunchKernelGGL(hist_kernel, dim3(64, NIMG), dim3(256), 0, stream, mnmx, out);
  hipLaunchKernelGGL(otsu_kernel, dim3(NIMG), dim3(256), 0, stream, mnmx, out, t);
  hipLaunchKernelGGL(mask_kernel, dim3(NIMG * NPIX / 4 / 256), dim3(256), 0, stream,
                     x, t, out);
}